// Round 7
// baseline (446.974 us; speedup 1.0000x reference)
//
#include <hip/hip_runtime.h>
#include <cstddef>
#include <cstdint>

#define HW 1024
#define NBATCH 32

typedef unsigned short ushort_t;
typedef unsigned int uint_t;
typedef short s16x8 __attribute__((ext_vector_type(8)));
typedef float f32x4 __attribute__((ext_vector_type(4)));
typedef float f32x16 __attribute__((ext_vector_type(16)));
typedef unsigned int u32x4 __attribute__((ext_vector_type(4)));

__device__ __forceinline__ float elu1(float z){ return z > 0.f ? z : __expf(z) - 1.f; }
__device__ __forceinline__ float sigm(float z){ return 1.f/(1.f+__expf(-z)); }
__device__ __forceinline__ ushort_t f2bf(float f){
  uint_t u = __builtin_bit_cast(uint_t, f);
  u += 0x7FFFu + ((u >> 16) & 1u);
  return (ushort_t)(u >> 16);
}
__device__ __forceinline__ float bf2f(ushort_t h){
  uint_t u = ((uint_t)h) << 16;
  return __builtin_bit_cast(float, u);
}
__device__ __forceinline__ uint_t cvtpk(float lo, float hi){
  uint_t r;
  asm("v_cvt_pk_bf16_f32 %0, %1, %2" : "=v"(r) : "v"(lo), "v"(hi));
  return r;
}
__device__ __forceinline__ void gload_lds16(const void* g, void* l){
  __builtin_amdgcn_global_load_lds((const __attribute__((address_space(1))) unsigned int*)g,
                                   (__attribute__((address_space(3))) unsigned int*)l, 16, 0, 0);
}

// gm: 0 = concat(x[3],ul[160],b[6]) (169 ch), 1 = concat(ul,b) (166), 2 = ul (160)
__device__ __forceinline__ const float* src_ptr(const float* x, const float* ul, const float* b,
                                                int n, int c, int gm){
  if (gm == 0){
    if (c < 3)   return x  + ((size_t)n*3   + c)*HW;
    if (c < 163) return ul + ((size_t)n*160 + (c-3))*HW;
    return b + ((size_t)n*6 + (c-163))*HW;
  } else if (gm == 1){
    if (c < 160) return ul + ((size_t)n*160 + c)*HW;
    return b + ((size_t)n*6 + (c-160))*HW;
  }
  return ul + ((size_t)n*160 + c)*HW;
}

// ---------------- concat_elu -> bf16 pixel-major; grid (pxblocks, P1/8) ----------------
template<int GM>
__global__ void k_act(const float* __restrict__ x, const float* __restrict__ ul,
                      const float* __restrict__ b,
                      ushort_t* __restrict__ out, int Cb, int P1, int CP){
  int pxg = blockIdx.x*256 + threadIdx.x;
  int n = pxg >> 10, hw = pxg & 1023;
  int c8 = blockIdx.y*8;
  ushort_t* orow = out + (size_t)pxg * CP;
  ushort_t pbuf[8], nbuf[8];
  #pragma unroll
  for (int j = 0; j < 8; ++j){
    int c = c8 + j;
    float s = 0.f;
    if (c < Cb) s = src_ptr(x, ul, b, n, c, GM)[hw];
    pbuf[j] = f2bf(elu1(s));
    nbuf[j] = f2bf(elu1(-s));
  }
  uint4 up, un;
  up.x = (uint_t)pbuf[0] | ((uint_t)pbuf[1]<<16);
  up.y = (uint_t)pbuf[2] | ((uint_t)pbuf[3]<<16);
  up.z = (uint_t)pbuf[4] | ((uint_t)pbuf[5]<<16);
  up.w = (uint_t)pbuf[6] | ((uint_t)pbuf[7]<<16);
  un.x = (uint_t)nbuf[0] | ((uint_t)nbuf[1]<<16);
  un.y = (uint_t)nbuf[2] | ((uint_t)nbuf[3]<<16);
  un.z = (uint_t)nbuf[4] | ((uint_t)nbuf[5]<<16);
  un.w = (uint_t)nbuf[6] | ((uint_t)nbuf[7]<<16);
  *(uint4*)(orow + c8)      = up;
  *(uint4*)(orow + P1 + c8) = un;
}

// ---------------- weight pre-convert ----------------
struct SPtrs { const float* p[12]; };
struct WCfg  { int dst[12], O[12], Kt[12], K1[12], P1[12], Opad[12], Kpad[12], Oh[12]; };

__global__ void k_wconv(SPtrs sp, WCfg c, ushort_t* __restrict__ Wb){
  int d = blockIdx.y;
  int O = c.O[d], Kt = c.Kt[d], K1 = c.K1[d], P1 = c.P1[d], Op = c.Opad[d], Kp = c.Kpad[d], Oh = c.Oh[d];
  ushort_t* dst = Wb + c.dst[d];
  int total = Op*Kp;
  if (d == 9){
    const float* wi = sp.p[9];
    const float* ws = sp.p[11];
    for (int i = blockIdx.x*256 + threadIdx.x; i < total; i += 32*256){
      int o = i / Kp, kk = i - o*Kp;
      float v = 0.f;
      if (o < O) v = (kk < 320) ? wi[(size_t)o*320 + kk] : ws[(size_t)o*160 + (kk - 320)];
      dst[i] = f2bf(v);
    }
    return;
  }
  const float* src = sp.p[d];
  int K2 = Kt - K1;
  for (int i = blockIdx.x*256 + threadIdx.x; i < total; i += 32*256){
    int o = i / Kp, kk = i - o*Kp;
    int k = (kk < K1) ? kk : ((kk >= P1 && kk < P1 + K2) ? (K1 + kk - P1) : -1);
    int so; bool rv;
    if (Oh > 0){
      if (o < 192){ so = o; rv = (o < Oh); }
      else        { so = Oh + (o - 192); rv = ((o - 192) < Oh); }
    } else { so = o; rv = (o < O); }
    float v = (rv && k >= 0) ? src[(size_t)so*Kt + k] : 0.f;
    dst[i] = f2bf(v);
  }
}

// ---------------- MFMA GEMM: 256px x 64o tile, A from L2->regs, B wave-private LDS ----------------
// EPI: 1 bf16 pixel-major(OP); 2 ce bf16 (neg at P1o, stride OP); 4 bf16 channel-major (OP rows/n);
//      5 fused grn-residual -> bf16 pixel-major(OP) [gm=P1o, paired Wo]; 6 fused -> fp32 ch-major out;
//      7 = EPI2 + bias2 (merged goWi|goWs); 8 = EPI2 dual-output (o0>=192 -> outv2, bias2)
template<int EPI>
__global__ __launch_bounds__(256) void k_gmm2(const ushort_t* __restrict__ Wb,
    const float* __restrict__ bias, const float* __restrict__ bias2,
    const ushort_t* __restrict__ act, void* __restrict__ outv, void* __restrict__ outv2,
    const float* __restrict__ xp, const float* __restrict__ ulp, const float* __restrict__ bp,
    int O, int Kpad, int CP, int OP, int P1o)
{
  __shared__ ushort_t Blds[4][2][2048];   // per-wave 2x4KB dbuf; reused as epilogue tile
  const int tid = threadIdx.x;
  const int w = tid >> 6, l = tid & 63;
  const int n = blockIdx.x >> 2, hw0 = (blockIdx.x & 3)*256;
  const bool FUSED = (EPI == 5 || EPI == 6);
  const int o0 = blockIdx.y*(FUSED ? 32 : 64);

  const ushort_t* actw = act + (size_t)(n*HW + hw0 + w*64)*CP;
  const ushort_t* Wbo  = Wb + (size_t)o0*Kpad;
  const size_t r2off = FUSED ? (size_t)192*Kpad : (size_t)32*Kpad;

#define STAGE2(bufi, ktv) do { \
    int cl_ = (l & 3) ^ ((l >> 4) & 2); \
    _Pragma("unroll") \
    for (int s_ = 0; s_ < 4; ++s_){ \
      const ushort_t* g_ = actw + (size_t)(s_*16 + (l>>2))*CP + (ktv)*32 + cl_*8; \
      gload_lds16(g_, &Blds[w][bufi][s_*512]); \
    } \
  } while(0)

  f32x4 acc[4][4];
  #pragma unroll
  for (int i = 0; i < 4; ++i)
    #pragma unroll
    for (int j = 0; j < 4; ++j) acc[i][j] = (f32x4){0.f,0.f,0.f,0.f};

  const int NT = Kpad >> 5;
  STAGE2(0, 0);
  for (int kt = 0; kt < NT; ++kt){
    int cur = kt & 1;
    const ushort_t* Ab = Wbo + (size_t)(l&15)*Kpad + kt*32 + (l>>4)*8;
    s16x8 a0 = *(const s16x8*)(Ab);
    s16x8 a1 = *(const s16x8*)(Ab + 16*Kpad);
    s16x8 a2 = *(const s16x8*)(Ab + r2off);
    s16x8 a3 = *(const s16x8*)(Ab + r2off + 16*Kpad);
    if (kt + 1 < NT){
      STAGE2(cur^1, kt+1);
      asm volatile("s_waitcnt vmcnt(4)" ::: "memory");
    } else {
      asm volatile("s_waitcnt vmcnt(0)" ::: "memory");   // drain: last tile has no prefetch behind it
    }
    const ushort_t* Bb = &Blds[w][cur][0];
    const int chp = ((l>>4) ^ ((l>>2)&2))*8;
    #pragma unroll
    for (int po = 0; po < 4; ++po){
      s16x8 bv = *(const s16x8*)(Bb + po*512 + (l&15)*32 + chp);
      acc[po][0] = __builtin_amdgcn_mfma_f32_16x16x32_bf16(a0, bv, acc[po][0], 0, 0, 0);
      acc[po][1] = __builtin_amdgcn_mfma_f32_16x16x32_bf16(a1, bv, acc[po][1], 0, 0, 0);
      acc[po][2] = __builtin_amdgcn_mfma_f32_16x16x32_bf16(a2, bv, acc[po][2], 0, 0, 0);
      acc[po][3] = __builtin_amdgcn_mfma_f32_16x16x32_bf16(a3, bv, acc[po][3], 0, 0, 0);
    }
  }
#undef STAGE2

  // D frag: col = l&15 (px), row = (l>>4)*4 + reg
  const int g = l >> 4, cc = l & 15;
  ushort_t* ep = &Blds[w][0][0];           // 4096 ushorts, wave-private (loads drained)
  const size_t pbase = (size_t)n*HW + hw0 + w*64;

  if (FUSED){
    const int gm = P1o;
    if (EPI == 6){
      #pragma unroll
      for (int oo = 0; oo < 2; ++oo){
        int ch = o0 + oo*16 + g*4;
        #pragma unroll
        for (int po = 0; po < 4; ++po){
          int px = hw0 + w*64 + po*16 + cc;
          #pragma unroll
          for (int i = 0; i < 4; ++i){
            int c = ch + i;
            if (c < O){
              float ga = acc[po][oo][i]   + bias[c];
              float gb = acc[po][oo+2][i] + bias[O + c];
              float s  = src_ptr(xp, ulp, bp, n, c, gm)[px];
              ((float*)outv)[((size_t)n*O + c)*HW + px] = s + ga*sigm(gb);
            }
          }
        }
      }
      return;
    }
    // EPI 5: LDS-transposed bf16 store, tile [64px][32ch] pitch 40 ushorts
    #pragma unroll
    for (int oo = 0; oo < 2; ++oo){
      #pragma unroll
      for (int po = 0; po < 4; ++po){
        int px = po*16 + cc;
        int pxg = hw0 + w*64 + px;
        float rr[4];
        #pragma unroll
        for (int i = 0; i < 4; ++i){
          int c = o0 + oo*16 + g*4 + i;
          float r = 0.f;
          if (c < O){
            float ga = acc[po][oo][i]   + bias[c];
            float gb = acc[po][oo+2][i] + bias[O + c];
            float s  = src_ptr(xp, ulp, bp, n, c, gm)[pxg];
            r = s + ga*sigm(gb);
          }
          rr[i] = r;
        }
        uint2 pk;
        pk.x = (uint_t)f2bf(rr[0]) | ((uint_t)f2bf(rr[1])<<16);
        pk.y = (uint_t)f2bf(rr[2]) | ((uint_t)f2bf(rr[3])<<16);
        *(uint2*)(ep + px*40 + oo*16 + g*4) = pk;
      }
    }
    #pragma unroll
    for (int it = 0; it < 4; ++it){
      int row = it*16 + (l>>2), ch = (l&3)*8;
      s16x8 v = *(const s16x8*)(ep + row*40 + ch);
      *(s16x8*)((ushort_t*)outv + (pbase + row)*OP + o0 + ch) = v;
    }
    return;
  }

  if (EPI == 2 || EPI == 7 || EPI == 8){
    ushort_t* oP = (ushort_t*)outv;
    const float* bsp = bias;
    int c0 = o0;
    if (EPI == 8 && o0 >= 192){ oP = (ushort_t*)outv2; bsp = bias2; c0 = o0 - 192; }
    #pragma unroll
    for (int round = 0; round < 2; ++round){
      int cb = round ? (P1o + c0) : c0;
      int maxc = (round ? OP : P1o) - cb; if (maxc > 64) maxc = 64;
      // fill [64px][64ch] tile, XOR-swizzled (byte bits 4-6 ^ px&7)
      #pragma unroll
      for (int oo = 0; oo < 4; ++oo){
        #pragma unroll
        for (int po = 0; po < 4; ++po){
          int px = po*16 + cc;
          float ev[4];
          #pragma unroll
          for (int i = 0; i < 4; ++i){
            int c = c0 + oo*16 + g*4 + i;
            float bv = 0.f;
            if (c < O){ bv = bsp[c]; if (EPI == 7) bv += bias2[c]; }
            float h = acc[po][oo][i] + bv;
            ev[i] = elu1(round ? -h : h);
          }
          uint2 pk;
          pk.x = (uint_t)f2bf(ev[0]) | ((uint_t)f2bf(ev[1])<<16);
          pk.y = (uint_t)f2bf(ev[2]) | ((uint_t)f2bf(ev[3])<<16);
          int off = oo*16 + g*4;
          *(uint2*)(ep + px*64 + (off ^ ((px&7)<<3))) = pk;
        }
      }
      #pragma unroll
      for (int it = 0; it < 8; ++it){
        int row = it*8 + (l>>3), ch = (l&7)*8;
        s16x8 v = *(const s16x8*)(ep + row*64 + (ch ^ ((row&7)<<3)));
        if (ch < maxc)
          *(s16x8*)(oP + (pbase + row)*OP + cb + ch) = v;
      }
    }
    return;
  }

  // EPI 1 / 4: small outputs, direct stores
  #pragma unroll
  for (int oo = 0; oo < 4; ++oo){
    int ch = o0 + oo*16 + g*4;
    if (ch >= O) continue;
    float b0 = bias[ch];
    float b1 = (ch+1 < O) ? bias[ch+1] : 0.f;
    float b2 = (ch+2 < O) ? bias[ch+2] : 0.f;
    float b3 = (ch+3 < O) ? bias[ch+3] : 0.f;
    #pragma unroll
    for (int po = 0; po < 4; ++po){
      int px = hw0 + w*64 + po*16 + cc;
      size_t pb = (size_t)n*HW + px;
      f32x4 a = acc[po][oo];
      float h0 = a[0]+b0, h1 = a[1]+b1, h2v = a[2]+b2, h3 = a[3]+b3;
      if (EPI == 1){
        uint2 pk;
        pk.x = (uint_t)f2bf(h0)  | ((uint_t)f2bf(h1)<<16);
        pk.y = (uint_t)f2bf(h2v) | ((uint_t)f2bf(h3)<<16);
        *(uint2*)((ushort_t*)outv + pb*OP + ch) = pk;
      } else {
        float hv[4] = {h0, h1, h2v, h3};
        #pragma unroll
        for (int i = 0; i < 4; ++i)
          if (ch + i < O) ((ushort_t*)outv)[((size_t)n*OP + ch + i)*HW + px] = f2bf(hv[i]);
      }
    }
  }
}

// ---------------- MFMA flash attention, 4-way split-K + LDS combine ----------------
__global__ __launch_bounds__(256) void k_attn2(const ushort_t* __restrict__ Kp,
    const ushort_t* __restrict__ Qp, const ushort_t* __restrict__ Vc, ushort_t* __restrict__ Mb){
  __shared__ float cmb[3][64][52];
  const int tid = threadIdx.x;
  const int wv = tid >> 6, l = tid & 63;
  const int qt = blockIdx.x, n = blockIdx.y;
  const int hi = l >> 5, qcol = l & 31;
  const int qg = qt*32 + qcol;

  s16x8 bq = *(const s16x8*)(Qp + ((size_t)(n*HW + qg))*16 + hi*8);

  f32x16 acc0, acc1, acc2;
  #pragma unroll
  for (int r = 0; r < 16; ++r){ acc0[r]=0.f; acc1[r]=0.f; acc2[r]=0.f; }
  float m = 0.f, S = 0.f;

  for (int kt = wv; kt <= qt; kt += 4){
    const int j0 = kt*32;
    s16x8 ak = *(const s16x8*)(Kp + ((size_t)(n*HW + j0 + qcol))*16 + hi*8);
    f32x16 zc;
    #pragma unroll
    for (int r = 0; r < 16; ++r) zc[r] = 0.f;
    f32x16 p = __builtin_amdgcn_mfma_f32_32x32x16_bf16(ak, bq, zc, 0, 0, 0);

    float ps[16];
    float tmax = -3.0e38f;
    const bool diag = (kt == qt);
    #pragma unroll
    for (int r = 0; r < 16; ++r){
      int kk = j0 + (r&3) + 8*(r>>2) + 4*hi;
      float sv = p[r];
      if (diag && kk >= qg) sv = -3.0e38f;
      ps[r] = sv;
      tmax = fmaxf(tmax, sv);
    }
    tmax = fmaxf(tmax, __shfl_xor(tmax, 32));
    if (tmax > m + 8.f){
      float f = __expf(m - tmax);
      S *= f;
      #pragma unroll
      for (int r = 0; r < 16; ++r){ acc0[r]*=f; acc1[r]*=f; acc2[r]*=f; }
      m = tmax;
    }
    float pe[16], ts = 0.f;
    #pragma unroll
    for (int r = 0; r < 16; ++r){ pe[r] = __expf(ps[r] - m); ts += pe[r]; }
    S += ts + __shfl_xor(ts, 32);

    uint_t w0 = cvtpk(pe[0],  pe[1]),  w1 = cvtpk(pe[2],  pe[3]);
    uint_t w2 = cvtpk(pe[4],  pe[5]),  w3 = cvtpk(pe[6],  pe[7]);
    uint_t w4 = cvtpk(pe[8],  pe[9]),  w5 = cvtpk(pe[10], pe[11]);
    uint_t w6 = cvtpk(pe[12], pe[13]), w7 = cvtpk(pe[14], pe[15]);
    uint_t o0 = __shfl_xor((int)w0, 32), o1 = __shfl_xor((int)w1, 32);
    uint_t o2 = __shfl_xor((int)w2, 32), o3 = __shfl_xor((int)w3, 32);
    uint_t o4 = __shfl_xor((int)w4, 32), o5 = __shfl_xor((int)w5, 32);
    uint_t o6 = __shfl_xor((int)w6, 32), o7 = __shfl_xor((int)w7, 32);
    u32x4 f0, f1;
    f0.x = hi ? o2 : w0; f0.y = hi ? o3 : w1; f0.z = hi ? w2 : o0; f0.w = hi ? w3 : o1;
    f1.x = hi ? o6 : w4; f1.y = hi ? o7 : w5; f1.z = hi ? w6 : o4; f1.w = hi ? w7 : o5;
    s16x8 pb0 = __builtin_bit_cast(s16x8, f0);
    s16x8 pb1 = __builtin_bit_cast(s16x8, f1);

    const ushort_t* vb = Vc + ((size_t)(n*96 + qcol))*HW + j0 + hi*8;
    s16x8 v00 = *(const s16x8*)(vb);
    s16x8 v01 = *(const s16x8*)(vb + 16);
    s16x8 v10 = *(const s16x8*)(vb + 32*HW);
    s16x8 v11 = *(const s16x8*)(vb + 32*HW + 16);
    s16x8 v20 = *(const s16x8*)(vb + 64*HW);
    s16x8 v21 = *(const s16x8*)(vb + 64*HW + 16);
    acc0 = __builtin_amdgcn_mfma_f32_32x32x16_bf16(v00, pb0, acc0, 0, 0, 0);
    acc0 = __builtin_amdgcn_mfma_f32_32x32x16_bf16(v01, pb1, acc0, 0, 0, 0);
    acc1 = __builtin_amdgcn_mfma_f32_32x32x16_bf16(v10, pb0, acc1, 0, 0, 0);
    acc1 = __builtin_amdgcn_mfma_f32_32x32x16_bf16(v11, pb1, acc1, 0, 0, 0);
    acc2 = __builtin_amdgcn_mfma_f32_32x32x16_bf16(v20, pb0, acc2, 0, 0, 0);
    acc2 = __builtin_amdgcn_mfma_f32_32x32x16_bf16(v21, pb1, acc2, 0, 0, 0);
  }

  if (wv){
    float* d = &cmb[wv-1][l][0];
    #pragma unroll
    for (int r = 0; r < 16; ++r){ d[r] = acc0[r]; d[16+r] = acc1[r]; d[32+r] = acc2[r]; }
    d[48] = m; d[49] = S;
  }
  __syncthreads();
  if (wv) return;

  #pragma unroll
  for (int w2 = 0; w2 < 3; ++w2){
    const float* s2 = &cmb[w2][l][0];
    float m2 = s2[48], S2 = s2[49];
    float M = fmaxf(m, m2);
    float f1 = __expf(m - M), f2 = __expf(m2 - M);
    S = S*f1 + S2*f2;
    #pragma unroll
    for (int r = 0; r < 16; ++r){
      acc0[r] = acc0[r]*f1 + s2[r]*f2;
      acc1[r] = acc1[r]*f1 + s2[16+r]*f2;
      acc2[r] = acc2[r]*f1 + s2[32+r]*f2;
    }
    m = M;
  }

  float Z = S + (float)(HW - qg)*__expf(-m);
  float inv = 1.f/(S + 1e-7f*Z);
  // write ce(att_v) into merged buffer cols [320,480): pos at 320+v, neg at 400+v
  ushort_t* mrow = Mb + (size_t)(n*HW + qg)*480 + 320;
  #pragma unroll
  for (int rg = 0; rg < 4; ++rg){
    int vb = 8*rg + 4*hi;
    float a0v[4], a1v[4];
    #pragma unroll
    for (int i = 0; i < 4; ++i){ a0v[i] = acc0[4*rg+i]*inv; a1v[i] = acc1[4*rg+i]*inv; }
    uint2 pp, pn;
    pp.x = (uint_t)f2bf(elu1(a0v[0]))  | ((uint_t)f2bf(elu1(a0v[1]))<<16);
    pp.y = (uint_t)f2bf(elu1(a0v[2]))  | ((uint_t)f2bf(elu1(a0v[3]))<<16);
    pn.x = (uint_t)f2bf(elu1(-a0v[0])) | ((uint_t)f2bf(elu1(-a0v[1]))<<16);
    pn.y = (uint_t)f2bf(elu1(-a0v[2])) | ((uint_t)f2bf(elu1(-a0v[3]))<<16);
    *(uint2*)(mrow + vb) = pp;
    *(uint2*)(mrow + 80 + vb) = pn;
    pp.x = (uint_t)f2bf(elu1(a1v[0]))  | ((uint_t)f2bf(elu1(a1v[1]))<<16);
    pp.y = (uint_t)f2bf(elu1(a1v[2]))  | ((uint_t)f2bf(elu1(a1v[3]))<<16);
    pn.x = (uint_t)f2bf(elu1(-a1v[0])) | ((uint_t)f2bf(elu1(-a1v[1]))<<16);
    pn.y = (uint_t)f2bf(elu1(-a1v[2])) | ((uint_t)f2bf(elu1(-a1v[3]))<<16);
    *(uint2*)(mrow + 32 + vb) = pp;
    *(uint2*)(mrow + 112 + vb) = pn;
    if (rg < 2){
      float a2v[4];
      #pragma unroll
      for (int i = 0; i < 4; ++i) a2v[i] = acc2[4*rg+i]*inv;
      pp.x = (uint_t)f2bf(elu1(a2v[0]))  | ((uint_t)f2bf(elu1(a2v[1]))<<16);
      pp.y = (uint_t)f2bf(elu1(a2v[2]))  | ((uint_t)f2bf(elu1(a2v[3]))<<16);
      pn.x = (uint_t)f2bf(elu1(-a2v[0])) | ((uint_t)f2bf(elu1(-a2v[1]))<<16);
      pn.y = (uint_t)f2bf(elu1(-a2v[2])) | ((uint_t)f2bf(elu1(-a2v[3]))<<16);
      *(uint2*)(mrow + 64 + vb) = pp;
      *(uint2*)(mrow + 144 + vb) = pn;
    }
  }
}

extern "C" void kernel_launch(void* const* d_in, const int* in_sizes, int n_in,
                              void* d_out, int out_size, void* d_ws, size_t ws_size,
                              hipStream_t stream) {
  const float* x    = (const float*)d_in[0];
  const float* ul   = (const float*)d_in[1];
  const float* bb   = (const float*)d_in[2];
  const float* gkWi = (const float*)d_in[3];  const float* gkbi = (const float*)d_in[4];
  const float* gkWo = (const float*)d_in[5];  const float* gkbo = (const float*)d_in[6];
  const float* gqWi = (const float*)d_in[7];  const float* gqbi = (const float*)d_in[8];
  const float* gqWo = (const float*)d_in[9];  const float* gqbo = (const float*)d_in[10];
  const float* gvWi = (const float*)d_in[11]; const float* gvbi = (const float*)d_in[12];
  const float* gvWo = (const float*)d_in[13]; const float* gvbo = (const float*)d_in[14];
  const float* nkW  = (const float*)d_in[15]; const float* nkb  = (const float*)d_in[16];
  const float* nqW  = (const float*)d_in[17]; const float* nqb  = (const float*)d_in[18];
  const float* nvW  = (const float*)d_in[19]; const float* nvb  = (const float*)d_in[20];
  const float* goWi = (const float*)d_in[21]; const float* gobi = (const float*)d_in[22];
  const float* goWs = (const float*)d_in[23]; const float* gobs = (const float*)d_in[24];
  const float* goWo = (const float*)d_in[25]; const float* gobo = (const float*)d_in[26];
  float* outp = (float*)d_out;
  char* wsb = (char*)d_ws;

  ushort_t* R0  = (ushort_t*)(wsb + 0);           // ce_xulb / ce_ulb (CP 352)
  ushort_t* R1k = (ushort_t*)(wsb + 23068672);    // Wi-K out / Wi-Q out (CP 352)
  ushort_t* R1v = (ushort_t*)(wsb + 46137344);    // Wi-V out (CP 352)
  ushort_t* R3  = (ushort_t*)(wsb + 69206016);    // grn-out (CP 192), reused per path
  ushort_t* Kp  = (ushort_t*)(wsb + 81788928);    // [32][1024][16] bf16
  ushort_t* Qp  = (ushort_t*)(wsb + 82837504);
  ushort_t* Vc  = (ushort_t*)(wsb + 83886080);    // [32][96][1024] bf16 chan-major
  ushort_t* M   = (ushort_t*)(wsb + 90177536);    // merged act: ce_ul [0,320) + ce_attv [320,480)
  ushort_t* R2  = (ushort_t*)(wsb + 121634816);   // ce of goWiWs out (CP 320)
  ushort_t* Wb  = (ushort_t*)(wsb + 142606336);   // bf16 weights

  // descs: 0 gkWi, 1 gvWi, 2 gkWo, 3 gvWo, 4 nkW, 5 nvW, 6 gqWi, 7 gqWo, 8 nqW, 9 goWiWs, 10 goWo
  static const int dDst[12] = {0,67584,135168,270336,405504,417792,442368,509952,645120,657408,749568,0};
  static const int dO[12]   = {169,169,338,338,16,80,166,332,16,160,320,0};
  static const int dKt[12]  = {338,338,338,338,169,169,332,332,166,0,320,0};
  static const int dK1[12]  = {169,169,169,169,169,169,166,166,166,0,320,0};
  static const int dP1[12]  = {176,176,176,176,9999,9999,176,176,9999,0,9999,0};
  static const int dOp[12]  = {192,192,384,384,64,128,192,384,64,192,384,0};
  static const int dKp[12]  = {352,352,352,352,192,192,352,352,192,480,320,0};
  static const int dOh[12]  = {0,0,169,169,0,0,0,166,0,0,160,0};

  SPtrs sp; WCfg wc;
  const float* srcs[12] = {gkWi,gvWi,gkWo,gvWo,nkW,nvW,gqWi,gqWo,nqW,goWi,goWo,goWs};
  for (int i = 0; i < 12; ++i){
    sp.p[i] = srcs[i];
    wc.dst[i]=dDst[i]; wc.O[i]=dO[i]; wc.Kt[i]=dKt[i]; wc.K1[i]=dK1[i];
    wc.P1[i]=dP1[i]; wc.Opad[i]=dOp[i]; wc.Kpad[i]=dKp[i]; wc.Oh[i]=dOh[i];
  }

  dim3 b256(256);
  k_wconv<<<dim3(32,11), b256, 0, stream>>>(sp, wc, Wb);

#define GMM2(EPI, DI, GY, B1, B2, ACT, OUT, OUT2, O_, CP_, OP_, P1O_) \
  k_gmm2<EPI><<<dim3(128, GY), b256, 0, stream>>>( \
    Wb + dDst[DI], B1, B2, (const ushort_t*)(ACT), OUT, OUT2, x, ul, bb, \
    O_, dKp[DI], CP_, OP_, P1O_)

  // ---- keys + values shared input ----
  k_act<0><<<dim3(128,22), b256, 0, stream>>>(x, ul, bb, R0, 169, 176, 352);
  GMM2(8, 0, 6, gkbi, gvbi, R0, R1k, R1v, 169, 352, 352, 176);   // merged gkWi|gvWi
  GMM2(5, 2, 6, gkbo, nullptr, R1k, R3, nullptr, 169, 352, 192, 0);
  GMM2(1, 4, 1, nkb, nullptr, R3, Kp, nullptr, 16, 192, 16, 0);
  GMM2(5, 3, 6, gvbo, nullptr, R1v, R3, nullptr, 169, 352, 192, 0);
  GMM2(4, 5, 2, nvb, nullptr, R3, Vc, nullptr, 80, 192, 96, 0);

  // ---- queries path ----
  k_act<1><<<dim3(128,22), b256, 0, stream>>>(x, ul, bb, R0, 166, 176, 352);
  GMM2(2, 6, 3, gqbi, nullptr, R0, R1k, nullptr, 166, 352, 352, 176);
  GMM2(5, 7, 6, gqbo, nullptr, R1k, R3, nullptr, 166, 352, 192, 1);
  GMM2(1, 8, 1, nqb, nullptr, R3, Qp, nullptr, 16, 192, 16, 0);

  // ---- ce(ul) into merged buffer (cols [0,320)) ----
  k_act<2><<<dim3(128,20), b256, 0, stream>>>(x, ul, bb, M, 160, 160, 480);

  // ---- attention (split-K, 4 waves/block): writes ce(att_v) into merged buffer ----
  k_attn2<<<dim3(32, 32), b256, 0, stream>>>(Kp, Qp, Vc, M);

  // ---- output grn ----
  GMM2(7, 9, 3, gobi, gobs, M, R2, nullptr, 160, 480, 320, 160);  // merged goWi|goWs + ce
  GMM2(6, 10, 5, gobo, nullptr, R2, outp, nullptr, 160, 320, 0, 2); // fused res2 final, gm=2
}